// Round 13
// baseline (183.293 us; speedup 1.0000x reference)
//
#include <hip/hip_runtime.h>
#include <math.h>

#define D 128
#define NCLS 32
#define TSLOT 16
#define CHUNK 256  // labels per sort block

typedef float f32x16 __attribute__((ext_vector_type(16)));
typedef short bf16x8 __attribute__((ext_vector_type(8)));

// ---------------- per-block label histogram ----------------
__global__ __launch_bounds__(64) void hist_blk_k(const int* __restrict__ label, int M,
                                                 int NB, int* __restrict__ blkhist_t) {
  __shared__ int h[NCLS];
  const int lane = threadIdx.x;
  const int b = blockIdx.x;
  if (lane < NCLS) h[lane] = 0;
  __syncthreads();
  const int s0 = b * CHUNK;
#pragma unroll
  for (int it = 0; it < CHUNK / 64; ++it) {
    int i = s0 + it * 64 + lane;
    if (i < M) atomicAdd(&h[label[i]], 1);
  }
  __syncthreads();
  if (lane < NCLS) blkhist_t[lane * NB + b] = h[lane];
}

// ---------------- fused: class totals + prefix + per-class block scan --------
// grid = NCLS blocks x 64 threads. Every block recomputes all class totals
// (L2-resident blkhist reads); block 0 publishes hist/cstart and zeroes the
// chol sync counter; block j writes base_t for its class.
__global__ __launch_bounds__(64) void base2_k(const int* __restrict__ blkhist_t, int NB,
                                              int* __restrict__ hist,
                                              int* __restrict__ cstart,
                                              int* __restrict__ sync_ctr,
                                              int* __restrict__ base_t) {
  const int j = blockIdx.x;
  const int lane = threadIdx.x;
  __shared__ int tot[NCLS];
#pragma unroll 1
  for (int q = 0; q < NCLS; ++q) {
    int s = 0;
    for (int b = lane; b < NB; b += 64) s += blkhist_t[q * NB + b];
#pragma unroll
    for (int off = 32; off > 0; off >>= 1) s += __shfl_down(s, off);
    if (lane == 0) tot[q] = s;
  }
  __syncthreads();
  int mystart = 0;
  if (lane == 0)
    for (int q = 0; q < j; ++q) mystart += tot[q];
  mystart = __shfl(mystart, 0);
  if (j == 0 && lane == 0) {
    int run = 0;
    for (int q = 0; q < NCLS; ++q) { cstart[q] = run; hist[q] = tot[q]; run += tot[q]; }
    cstart[NCLS] = run;
    *sync_ctr = 0;
  }
  const int K = (NB + 63) / 64;
  int vals[32];
  int run = 0;
  for (int k = 0; k < K; ++k) {
    int b = lane * K + k;
    int v = (b < NB) ? blkhist_t[j * NB + b] : 0;
    vals[k] = v;
    run += v;
  }
  int incl = run;
  for (int off = 1; off < 64; off <<= 1) {
    int o = __shfl_up(incl, off);
    if (lane >= off) incl += o;
  }
  int pos = mystart + (incl - run);
  for (int k = 0; k < K; ++k) {
    int b = lane * K + k;
    if (b < NB) base_t[j * NB + b] = pos;
    pos += vals[k];
  }
}

// ---------------- stable, atomic-free scatter (1 wave / block) ----------------
__global__ __launch_bounds__(64) void scatter2_k(const int* __restrict__ label, int M,
                                                 int NB, const int* __restrict__ base_t,
                                                 int* __restrict__ idxbuf) {
  __shared__ int cur[NCLS];
  const int b = blockIdx.x;
  const int lane = threadIdx.x;
  if (lane < NCLS) cur[lane] = base_t[lane * NB + b];
  __syncthreads();
  const int s0 = b * CHUNK;
#pragma unroll
  for (int it = 0; it < CHUNK / 64; ++it) {
    int i = s0 + it * 64 + lane;
    int j = (i < M) ? label[i] : -1;
    unsigned long long mask = 0;
#pragma unroll
    for (int q = 0; q < NCLS; ++q) {
      unsigned long long mm = __ballot(j == q);
      if (j == q) mask = mm;
    }
    if (j >= 0) {
      int myoff = __popcll(mask & ((1ull << lane) - 1ull));
      int basec = cur[j];
      idxbuf[basec + myoff] = i;
      if (myoff == 0) cur[j] = basec + __popcll(mask);
    }
    __syncthreads();
  }
}

// ---------------- fp32 -> (hi, lo) bf16 split, RNE ----------------
__device__ inline void bsplit(float x, short& hi, short& lo) {
  unsigned u = __float_as_uint(x);
  unsigned rh = u + 0x7fffu + ((u >> 16) & 1u);
  unsigned short h = (unsigned short)(rh >> 16);
  float hf = __uint_as_float((unsigned)h << 16);
  float l = x - hf;  // exact
  unsigned ul = __float_as_uint(l);
  unsigned rl = ul + 0x7fffu + ((ul >> 16) & 1u);
  hi = (short)h;
  lo = (short)(rl >> 16);
}

// ---------------- per-class Gram via bf16-split MFMA (R11 structure) ----------
__global__ __launch_bounds__(1024, 8) void cov_k(const float* __restrict__ Z,
                                                 const int* __restrict__ idxbuf,
                                                 const int* __restrict__ hist,
                                                 const int* __restrict__ cstart,
                                                 float* __restrict__ partials) {
  __shared__ __attribute__((aligned(16))) char arena[33792];
  char* const ThiB = arena;
  char* const TloB = arena + 16896;

  const int b = blockIdx.x;
  const int cls = b / TSLOT, slot = b % TSLOT;
  const int t = threadIdx.x;
  const int lane = t & 63;
  const int w = t >> 6;
  const int r = w >> 2;  // A row-strip 0..3
  const int cq = w & 3;  // B col-strip 0..3

  const int col4 = t & 31;  // stages cols 4*col4 .. +3
  const int rg = t >> 5;    // stages rows rg*2, rg*2+1 (k dim)
  const int wbase = (((rg >> 3) * 4 + (col4 >> 3)) * 2 + ((rg >> 2) & 1)) * 528 +
                    (col4 & 7) * 16 + (rg & 3) * 4;

  const int mj = hist[cls];
  const int seg0 = cstart[cls];
  const int segend = seg0 + mj;
  const int nch = (mj + 63) / 64;

  f32x16 acc;
#pragma unroll
  for (int i = 0; i < 16; ++i) acc[i] = 0.f;

  const int n = lane & 31;
  const int poff = ((n >> 2) + 8 * (n & 3)) * 16 + (lane >> 5) * 528;

  float4 pv[2];
  int idxn0 = 0, idxn1 = 0;
  {
    const int ch = slot;
    const int r0 = seg0 + ch * 64;
    int i0 = 0, i1 = 0;
    if (ch < nch) {
      int g0 = r0 + rg * 2, g1 = r0 + rg * 2 + 1;
      if (g0 < segend) i0 = idxbuf[g0];
      if (g1 < segend) i1 = idxbuf[g1];
      pv[0] = (g0 < segend) ? *(const float4*)(Z + (size_t)i0 * D + col4 * 4)
                            : make_float4(0.f, 0.f, 0.f, 0.f);
      pv[1] = (g1 < segend) ? *(const float4*)(Z + (size_t)i1 * D + col4 * 4)
                            : make_float4(0.f, 0.f, 0.f, 0.f);
    } else {
      pv[0] = make_float4(0.f, 0.f, 0.f, 0.f);
      pv[1] = make_float4(0.f, 0.f, 0.f, 0.f);
    }
    const int chn = ch + TSLOT;
    const int r1 = seg0 + chn * 64;
    if (chn < nch) {
      int g0 = r1 + rg * 2, g1 = r1 + rg * 2 + 1;
      if (g0 < segend) idxn0 = idxbuf[g0];
      if (g1 < segend) idxn1 = idxbuf[g1];
    }
  }

#pragma unroll 1
  for (int ch = slot; ch < nch; ch += TSLOT) {
    __syncthreads();  // arena free (prior MFMA done by all waves)
    {
      float xs[2][4];
      xs[0][0] = pv[0].x; xs[0][1] = pv[0].y; xs[0][2] = pv[0].z; xs[0][3] = pv[0].w;
      xs[1][0] = pv[1].x; xs[1][1] = pv[1].y; xs[1][2] = pv[1].z; xs[1][3] = pv[1].w;
#pragma unroll
      for (int j = 0; j < 4; ++j) {
        short h0, l0, h1, l1;
        bsplit(xs[0][j], h0, l0);
        bsplit(xs[1][j], h1, l1);
        *(short2*)(ThiB + wbase + j * 128) = make_short2(h0, h1);
        *(short2*)(TloB + wbase + j * 128) = make_short2(l0, l1);
      }
    }
    __syncthreads();  // arena staged by all waves
    {
      const int chn = ch + TSLOT;
      const int r1 = seg0 + chn * 64;
      int g0 = r1 + rg * 2, g1 = r1 + rg * 2 + 1;
      bool v0 = (chn < nch) && (g0 < segend);
      bool v1 = (chn < nch) && (g1 < segend);
      pv[0] = v0 ? *(const float4*)(Z + (size_t)idxn0 * D + col4 * 4)
                 : make_float4(0.f, 0.f, 0.f, 0.f);
      pv[1] = v1 ? *(const float4*)(Z + (size_t)idxn1 * D + col4 * 4)
                 : make_float4(0.f, 0.f, 0.f, 0.f);
      const int chn2 = ch + 2 * TSLOT;
      const int r2 = seg0 + chn2 * 64;
      if (chn2 < nch) {
        int h0 = r2 + rg * 2, h1 = r2 + rg * 2 + 1;
        if (h0 < segend) idxn0 = idxbuf[h0];
        if (h1 < segend) idxn1 = idxbuf[h1];
      }
    }
#pragma unroll
    for (int kk = 0; kk < 4; ++kk) {
      const int ab = (kk * 4 + r) * 1056 + poff;
      const int bb = (kk * 4 + cq) * 1056 + poff;
      bf16x8 ahi = *(const bf16x8*)(ThiB + ab);
      bf16x8 alo = *(const bf16x8*)(TloB + ab);
      bf16x8 bhi = *(const bf16x8*)(ThiB + bb);
      bf16x8 blo = *(const bf16x8*)(TloB + bb);
      acc = __builtin_amdgcn_mfma_f32_32x32x16_bf16(ahi, bhi, acc, 0, 0, 0);
      acc = __builtin_amdgcn_mfma_f32_32x32x16_bf16(ahi, blo, acc, 0, 0, 0);
      acc = __builtin_amdgcn_mfma_f32_32x32x16_bf16(alo, bhi, acc, 0, 0, 0);
    }
  }

  size_t base = (size_t)b * (D * D);
#pragma unroll
  for (int i = 0; i < 16; ++i) {
    int prow = r * 32 + (i & 3) + 8 * (i >> 2) + 4 * (lane >> 5);
    int qcol = cq * 32 + (lane & 31);
    partials[base + (size_t)prow * D + qcol] = acc[i];
  }
}

// ---------------- reduce partials -> 32 class covs + total cov ----------------
__global__ void reduce_k(const float* __restrict__ partials, float* __restrict__ covs) {
  int e = blockIdx.x * blockDim.x + threadIdx.x;
  double tot = 0.0;
  for (int j = 0; j < NCLS; ++j) {
    double s = 0.0;
    for (int t = 0; t < TSLOT; ++t)
      s += (double)partials[(size_t)(j * TSLOT + t) * (D * D) + e];
    covs[(size_t)j * (D * D) + e] = (float)s;
    tot += s;
  }
  covs[(size_t)NCLS * (D * D) + e] = (float)tot;
}

// ---------------- blocked Cholesky logdet + fused final combine --------------
__global__ __launch_bounds__(256, 1) void chol_k(const float* __restrict__ covs,
                                                 const int* __restrict__ hist,
                                                 int Mtot, double* __restrict__ results,
                                                 int* __restrict__ sync_ctr,
                                                 float* __restrict__ out) {
  __shared__ float As[128][132];
  __shared__ float PlT[32][36];  // PlT[i][jj] = L11[jj][i]
  __shared__ float invd[32];
  __shared__ float colbuf[32];
  __shared__ double red[64];
  __shared__ __attribute__((aligned(16))) short Thi[96 * 40];  // 80B pitch
  __shared__ __attribute__((aligned(16))) short Tlo[96 * 40];
  const int j = blockIdx.x;
  const float* A = covs + (size_t)j * (D * D);
  const int tid = threadIdx.x;
  const int lane = tid & 63;
  const int wv = tid >> 6;

#pragma unroll
  for (int it = 0; it < 16; ++it) {
    int e = it * 1024 + tid * 4;
    int r = e >> 7, c = e & 127;
    *(float4*)&As[r][c] = *(const float4*)&A[e];
  }
  __syncthreads();

  double lda = 0.0;
#pragma unroll 1
  for (int p = 0; p < 4; ++p) {
    const int pbase = p * 32;
    const int N2 = 96 - pbase;
    if (wv == 0) {
      const int l = lane & 31;
      float row[32];
#pragma unroll
      for (int c4 = 0; c4 < 8; ++c4) {
        float4 v = *(const float4*)&As[pbase + l][pbase + c4 * 4];
        row[c4 * 4 + 0] = v.x; row[c4 * 4 + 1] = v.y;
        row[c4 * 4 + 2] = v.z; row[c4 * 4 + 3] = v.w;
      }
      float mypiv = 1.f, myinv = 0.f;
#pragma unroll
      for (int k = 0; k < 32; ++k) {
        colbuf[l] = row[k];
        float cb[32];
#pragma unroll
        for (int q = 0; q < 8; ++q) {
          float4 v = *(const float4*)&colbuf[q * 4];
          cb[q * 4 + 0] = v.x; cb[q * 4 + 1] = v.y;
          cb[q * 4 + 2] = v.z; cb[q * 4 + 3] = v.w;
        }
        float piv = cb[k];
        float inv = rsqrtf(piv);
        inv = inv * (1.5f - 0.5f * piv * inv * inv);
        if (lane == k) { mypiv = piv; myinv = inv; }
        float tmul = row[k] * (inv * inv);
#pragma unroll
        for (int c = k + 1; c < 32; ++c)
          row[c] = fmaf(-tmul, cb[c], row[c]);
        row[k] *= inv;
      }
      if (lane < 32) {
#pragma unroll
        for (int c = 0; c < 32; ++c) PlT[c][lane] = row[c];
        invd[lane] = myinv;
      }
      lda += log((double)mypiv);
    }
    __syncthreads();
    if (tid < N2) {
      const int R = pbase + 32 + tid;
      float s[32];
#pragma unroll
      for (int c4 = 0; c4 < 8; ++c4) {
        float4 v = *(const float4*)&As[R][pbase + c4 * 4];
        s[c4 * 4 + 0] = v.x; s[c4 * 4 + 1] = v.y;
        s[c4 * 4 + 2] = v.z; s[c4 * 4 + 3] = v.w;
      }
#pragma unroll
      for (int i = 0; i < 32; ++i) {
        float xi = s[i] * invd[i];
        s[i] = xi;
#pragma unroll
        for (int jj = i + 1; jj < 32; ++jj)
          s[jj] = fmaf(-xi, PlT[i][jj], s[jj]);
      }
      unsigned hp[16], lp[16];
#pragma unroll
      for (int q = 0; q < 16; ++q) {
        short ha, la, hb, lb;
        bsplit(s[2 * q], ha, la);
        bsplit(s[2 * q + 1], hb, lb);
        hp[q] = (unsigned)(unsigned short)ha | ((unsigned)(unsigned short)hb << 16);
        lp[q] = (unsigned)(unsigned short)la | ((unsigned)(unsigned short)lb << 16);
      }
#pragma unroll
      for (int q = 0; q < 4; ++q) {
        *(int4*)&Thi[tid * 40 + q * 8] =
            make_int4(hp[4 * q], hp[4 * q + 1], hp[4 * q + 2], hp[4 * q + 3]);
        *(int4*)&Tlo[tid * 40 + q * 8] =
            make_int4(lp[4 * q], lp[4 * q + 1], lp[4 * q + 2], lp[4 * q + 3]);
      }
    }
    __syncthreads();
    const int nstr = N2 >> 5;
    if (wv < nstr) {
      const int l31 = lane & 31;
      const int h = lane >> 5;
      const int arow = wv * 32 + l31;
#pragma unroll 1
      for (int ct = 0; ct < nstr; ++ct) {
        const int brow = ct * 32 + l31;
        f32x16 acc;
#pragma unroll
        for (int i = 0; i < 16; ++i) acc[i] = 0.f;
#pragma unroll
        for (int ks = 0; ks < 2; ++ks) {
          const int off = ks * 16 + h * 8;
          bf16x8 ahi = *(const bf16x8*)&Thi[arow * 40 + off];
          bf16x8 alo = *(const bf16x8*)&Tlo[arow * 40 + off];
          bf16x8 bhi = *(const bf16x8*)&Thi[brow * 40 + off];
          bf16x8 blo = *(const bf16x8*)&Tlo[brow * 40 + off];
          acc = __builtin_amdgcn_mfma_f32_32x32x16_bf16(ahi, bhi, acc, 0, 0, 0);
          acc = __builtin_amdgcn_mfma_f32_32x32x16_bf16(ahi, blo, acc, 0, 0, 0);
          acc = __builtin_amdgcn_mfma_f32_32x32x16_bf16(alo, bhi, acc, 0, 0, 0);
        }
#pragma unroll
        for (int i = 0; i < 16; ++i) {
          int rr = pbase + 32 + wv * 32 + (i & 3) + 8 * (i >> 2) + 4 * h;
          int cc = pbase + 32 + ct * 32 + l31;
          As[rr][cc] -= acc[i];
        }
      }
    }
    __syncthreads();
  }

  if (wv == 0) red[lane] = lda;
  __syncthreads();
  if (tid == 0) {
    double lsum = 0.0;
    for (int i = 0; i < 64; ++i) lsum += red[i];
    double res;
    if (j < NCLS) {
      int mj = hist[j];
      res = 0.0;
      if (mj > 0) {
        double cj = (double)D / ((double)mj * 0.01);
        res = ((double)D * log(cj) + lsum) * (double)mj / (2.0 * (double)Mtot);
      }
    } else {
      double c = (double)D / ((double)Mtot * 0.01);
      res = ((double)D * log(c) + lsum) * 0.5;
    }
    results[j] = res;
    __threadfence();  // publish before signaling
    int done = atomicAdd(sync_ctr, 1);
    if (done == NCLS) {  // last of NCLS+1 blocks
      __threadfence();
      volatile double* vr = (volatile double*)results;
      double ssum = 0.0;
      for (int q = 0; q < NCLS; ++q) ssum += vr[q];
      out[0] = (float)(ssum - vr[NCLS]);
    }
  }
}

extern "C" void kernel_launch(void* const* d_in, const int* in_sizes, int n_in,
                              void* d_out, int out_size, void* d_ws, size_t ws_size,
                              hipStream_t stream) {
  const float* Z = (const float*)d_in[0];
  const int* label = (const int*)d_in[1];
  const int Mtot = in_sizes[1];
  float* out = (float*)d_out;
  const int NB = (Mtot + CHUNK - 1) / CHUNK;

  char* ws = (char*)d_ws;
  int* hist = (int*)(ws + 0);
  int* cstart = (int*)(ws + 256);
  int* sync_ctr = (int*)(ws + 448);
  double* results = (double*)(ws + 512);
  int* idxbuf = (int*)(ws + 1024);
  float* partials = (float*)(ws + 1024 + (size_t)Mtot * sizeof(int));
  float* covs = partials + (size_t)NCLS * TSLOT * D * D;
  int* blkhist_t = (int*)partials;  // aliased, dead before cov_k
  int* base_t = blkhist_t + (size_t)NCLS * NB;

  hist_blk_k<<<NB, 64, 0, stream>>>(label, Mtot, NB, blkhist_t);
  base2_k<<<NCLS, 64, 0, stream>>>(blkhist_t, NB, hist, cstart, sync_ctr, base_t);
  scatter2_k<<<NB, 64, 0, stream>>>(label, Mtot, NB, base_t, idxbuf);
  cov_k<<<NCLS * TSLOT, 1024, 0, stream>>>(Z, idxbuf, hist, cstart, partials);
  reduce_k<<<(D * D) / 256, 256, 0, stream>>>(partials, covs);
  chol_k<<<NCLS + 1, 256, 0, stream>>>(covs, hist, Mtot, results, sync_ctr, out);
}

// Round 14
// 125.906 us; speedup vs baseline: 1.4558x; 1.4558x over previous
//
#include <hip/hip_runtime.h>
#include <math.h>

#define D 128
#define NCLS 32
#define TSLOT 16
#define CHUNK 256  // labels per sort block

typedef float f32x16 __attribute__((ext_vector_type(16)));
typedef short bf16x8 __attribute__((ext_vector_type(8)));

// ---------------- zero counters ----------------
__global__ void zero_k(int* hist, int* sync_ctr) {
  int t = threadIdx.x;
  if (t < NCLS) hist[t] = 0;
  if (t == NCLS) *sync_ctr = 0;
}

// ---------------- per-block label histogram (+ global hist) ----------------
__global__ __launch_bounds__(64) void hist_blk_k(const int* __restrict__ label, int M,
                                                 int NB, int* __restrict__ blkhist_t,
                                                 int* __restrict__ hist) {
  __shared__ int h[NCLS];
  const int lane = threadIdx.x;
  const int b = blockIdx.x;
  if (lane < NCLS) h[lane] = 0;
  __syncthreads();
  const int s0 = b * CHUNK;
#pragma unroll
  for (int it = 0; it < CHUNK / 64; ++it) {
    int i = s0 + it * 64 + lane;
    if (i < M) atomicAdd(&h[label[i]], 1);
  }
  __syncthreads();
  if (lane < NCLS) {
    blkhist_t[lane * NB + b] = h[lane];
    atomicAdd(&hist[lane], h[lane]);
  }
}

// ---------------- per-class block scan (prefix fused via shfl over hist) -----
__global__ __launch_bounds__(64) void base_k(const int* __restrict__ hist,
                                             const int* __restrict__ blkhist_t, int NB,
                                             int* __restrict__ cstart,
                                             int* __restrict__ base_t) {
  const int j = blockIdx.x;
  const int lane = threadIdx.x;
  // class-offset prefix: 32 parallel loads + shfl scan (no serial load chain)
  int h = (lane < NCLS) ? hist[lane] : 0;
  int incl = h;
#pragma unroll
  for (int off = 1; off < 32; off <<= 1) {
    int o = __shfl_up(incl, off);
    if ((lane & 31) >= off) incl += o;
  }
  int excl = incl - h;
  const int mystart = __shfl(excl, j);
  if (j == 0 && lane < NCLS) {
    cstart[lane] = excl;
    if (lane == NCLS - 1) cstart[NCLS] = incl;
  }
  const int K = (NB + 63) / 64;
  int vals[32];
  int run = 0;
  for (int k = 0; k < K; ++k) {
    int b = lane * K + k;
    int v = (b < NB) ? blkhist_t[j * NB + b] : 0;
    vals[k] = v;
    run += v;
  }
  int incl2 = run;
  for (int off = 1; off < 64; off <<= 1) {
    int o = __shfl_up(incl2, off);
    if (lane >= off) incl2 += o;
  }
  int pos = mystart + (incl2 - run);
  for (int k = 0; k < K; ++k) {
    int b = lane * K + k;
    if (b < NB) base_t[j * NB + b] = pos;
    pos += vals[k];
  }
}

// ---------------- stable, atomic-free scatter (1 wave / block) ----------------
__global__ __launch_bounds__(64) void scatter2_k(const int* __restrict__ label, int M,
                                                 int NB, const int* __restrict__ base_t,
                                                 int* __restrict__ idxbuf) {
  __shared__ int cur[NCLS];
  const int b = blockIdx.x;
  const int lane = threadIdx.x;
  if (lane < NCLS) cur[lane] = base_t[lane * NB + b];
  __syncthreads();
  const int s0 = b * CHUNK;
#pragma unroll
  for (int it = 0; it < CHUNK / 64; ++it) {
    int i = s0 + it * 64 + lane;
    int j = (i < M) ? label[i] : -1;
    unsigned long long mask = 0;
#pragma unroll
    for (int q = 0; q < NCLS; ++q) {
      unsigned long long mm = __ballot(j == q);
      if (j == q) mask = mm;
    }
    if (j >= 0) {
      int myoff = __popcll(mask & ((1ull << lane) - 1ull));
      int basec = cur[j];
      idxbuf[basec + myoff] = i;
      if (myoff == 0) cur[j] = basec + __popcll(mask);
    }
    __syncthreads();
  }
}

// ---------------- fp32 -> (hi, lo) bf16 split, RNE ----------------
__device__ inline void bsplit(float x, short& hi, short& lo) {
  unsigned u = __float_as_uint(x);
  unsigned rh = u + 0x7fffu + ((u >> 16) & 1u);
  unsigned short h = (unsigned short)(rh >> 16);
  float hf = __uint_as_float((unsigned)h << 16);
  float l = x - hf;  // exact
  unsigned ul = __float_as_uint(l);
  unsigned rl = ul + 0x7fffu + ((ul >> 16) & 1u);
  hi = (short)h;
  lo = (short)(rl >> 16);
}

// ---------------- per-class Gram via bf16-split MFMA (R11 structure) ----------
__global__ __launch_bounds__(1024, 8) void cov_k(const float* __restrict__ Z,
                                                 const int* __restrict__ idxbuf,
                                                 const int* __restrict__ hist,
                                                 const int* __restrict__ cstart,
                                                 float* __restrict__ partials) {
  __shared__ __attribute__((aligned(16))) char arena[33792];
  char* const ThiB = arena;
  char* const TloB = arena + 16896;

  const int b = blockIdx.x;
  const int cls = b / TSLOT, slot = b % TSLOT;
  const int t = threadIdx.x;
  const int lane = t & 63;
  const int w = t >> 6;
  const int r = w >> 2;  // A row-strip 0..3
  const int cq = w & 3;  // B col-strip 0..3

  const int col4 = t & 31;  // stages cols 4*col4 .. +3
  const int rg = t >> 5;    // stages rows rg*2, rg*2+1 (k dim)
  const int wbase = (((rg >> 3) * 4 + (col4 >> 3)) * 2 + ((rg >> 2) & 1)) * 528 +
                    (col4 & 7) * 16 + (rg & 3) * 4;

  const int mj = hist[cls];
  const int seg0 = cstart[cls];
  const int segend = seg0 + mj;
  const int nch = (mj + 63) / 64;

  f32x16 acc;
#pragma unroll
  for (int i = 0; i < 16; ++i) acc[i] = 0.f;

  const int n = lane & 31;
  const int poff = ((n >> 2) + 8 * (n & 3)) * 16 + (lane >> 5) * 528;

  float4 pv[2];
  int idxn0 = 0, idxn1 = 0;
  {
    const int ch = slot;
    const int r0 = seg0 + ch * 64;
    int i0 = 0, i1 = 0;
    if (ch < nch) {
      int g0 = r0 + rg * 2, g1 = r0 + rg * 2 + 1;
      if (g0 < segend) i0 = idxbuf[g0];
      if (g1 < segend) i1 = idxbuf[g1];
      pv[0] = (g0 < segend) ? *(const float4*)(Z + (size_t)i0 * D + col4 * 4)
                            : make_float4(0.f, 0.f, 0.f, 0.f);
      pv[1] = (g1 < segend) ? *(const float4*)(Z + (size_t)i1 * D + col4 * 4)
                            : make_float4(0.f, 0.f, 0.f, 0.f);
    } else {
      pv[0] = make_float4(0.f, 0.f, 0.f, 0.f);
      pv[1] = make_float4(0.f, 0.f, 0.f, 0.f);
    }
    const int chn = ch + TSLOT;
    const int r1 = seg0 + chn * 64;
    if (chn < nch) {
      int g0 = r1 + rg * 2, g1 = r1 + rg * 2 + 1;
      if (g0 < segend) idxn0 = idxbuf[g0];
      if (g1 < segend) idxn1 = idxbuf[g1];
    }
  }

#pragma unroll 1
  for (int ch = slot; ch < nch; ch += TSLOT) {
    __syncthreads();  // arena free (prior MFMA done by all waves)
    {
      float xs[2][4];
      xs[0][0] = pv[0].x; xs[0][1] = pv[0].y; xs[0][2] = pv[0].z; xs[0][3] = pv[0].w;
      xs[1][0] = pv[1].x; xs[1][1] = pv[1].y; xs[1][2] = pv[1].z; xs[1][3] = pv[1].w;
#pragma unroll
      for (int j = 0; j < 4; ++j) {
        short h0, l0, h1, l1;
        bsplit(xs[0][j], h0, l0);
        bsplit(xs[1][j], h1, l1);
        *(short2*)(ThiB + wbase + j * 128) = make_short2(h0, h1);
        *(short2*)(TloB + wbase + j * 128) = make_short2(l0, l1);
      }
    }
    __syncthreads();  // arena staged by all waves
    {
      const int chn = ch + TSLOT;
      const int r1 = seg0 + chn * 64;
      int g0 = r1 + rg * 2, g1 = r1 + rg * 2 + 1;
      bool v0 = (chn < nch) && (g0 < segend);
      bool v1 = (chn < nch) && (g1 < segend);
      pv[0] = v0 ? *(const float4*)(Z + (size_t)idxn0 * D + col4 * 4)
                 : make_float4(0.f, 0.f, 0.f, 0.f);
      pv[1] = v1 ? *(const float4*)(Z + (size_t)idxn1 * D + col4 * 4)
                 : make_float4(0.f, 0.f, 0.f, 0.f);
      const int chn2 = ch + 2 * TSLOT;
      const int r2 = seg0 + chn2 * 64;
      if (chn2 < nch) {
        int h0 = r2 + rg * 2, h1 = r2 + rg * 2 + 1;
        if (h0 < segend) idxn0 = idxbuf[h0];
        if (h1 < segend) idxn1 = idxbuf[h1];
      }
    }
#pragma unroll
    for (int kk = 0; kk < 4; ++kk) {
      const int ab = (kk * 4 + r) * 1056 + poff;
      const int bb = (kk * 4 + cq) * 1056 + poff;
      bf16x8 ahi = *(const bf16x8*)(ThiB + ab);
      bf16x8 alo = *(const bf16x8*)(TloB + ab);
      bf16x8 bhi = *(const bf16x8*)(ThiB + bb);
      bf16x8 blo = *(const bf16x8*)(TloB + bb);
      acc = __builtin_amdgcn_mfma_f32_32x32x16_bf16(ahi, bhi, acc, 0, 0, 0);
      acc = __builtin_amdgcn_mfma_f32_32x32x16_bf16(ahi, blo, acc, 0, 0, 0);
      acc = __builtin_amdgcn_mfma_f32_32x32x16_bf16(alo, bhi, acc, 0, 0, 0);
    }
  }

  size_t base = (size_t)b * (D * D);
#pragma unroll
  for (int i = 0; i < 16; ++i) {
    int prow = r * 32 + (i & 3) + 8 * (i >> 2) + 4 * (lane >> 5);
    int qcol = cq * 32 + (lane & 31);
    partials[base + (size_t)prow * D + qcol] = acc[i];
  }
}

// ---------------- reduce partials -> 32 class covs + total cov ----------------
__global__ void reduce_k(const float* __restrict__ partials, float* __restrict__ covs) {
  int e = blockIdx.x * blockDim.x + threadIdx.x;
  double tot = 0.0;
  for (int j = 0; j < NCLS; ++j) {
    double s = 0.0;
    for (int t = 0; t < TSLOT; ++t)
      s += (double)partials[(size_t)(j * TSLOT + t) * (D * D) + e];
    covs[(size_t)j * (D * D) + e] = (float)s;
    tot += s;
  }
  covs[(size_t)NCLS * (D * D) + e] = (float)tot;
}

// ---------------- blocked Cholesky logdet + fused final combine --------------
__global__ __launch_bounds__(256, 1) void chol_k(const float* __restrict__ covs,
                                                 const int* __restrict__ hist,
                                                 int Mtot, double* __restrict__ results,
                                                 int* __restrict__ sync_ctr,
                                                 float* __restrict__ out) {
  __shared__ float As[128][132];
  __shared__ float PlT[32][36];  // PlT[i][jj] = L11[jj][i]
  __shared__ float invd[32];
  __shared__ float colbuf[32];
  __shared__ double red[64];
  __shared__ __attribute__((aligned(16))) short Thi[96 * 40];  // 80B pitch
  __shared__ __attribute__((aligned(16))) short Tlo[96 * 40];
  const int j = blockIdx.x;
  const float* A = covs + (size_t)j * (D * D);
  const int tid = threadIdx.x;
  const int lane = tid & 63;
  const int wv = tid >> 6;

#pragma unroll
  for (int it = 0; it < 16; ++it) {
    int e = it * 1024 + tid * 4;
    int r = e >> 7, c = e & 127;
    *(float4*)&As[r][c] = *(const float4*)&A[e];
  }
  __syncthreads();

  double lda = 0.0;
#pragma unroll 1
  for (int p = 0; p < 4; ++p) {
    const int pbase = p * 32;
    const int N2 = 96 - pbase;
    if (wv == 0) {
      const int l = lane & 31;
      float row[32];
#pragma unroll
      for (int c4 = 0; c4 < 8; ++c4) {
        float4 v = *(const float4*)&As[pbase + l][pbase + c4 * 4];
        row[c4 * 4 + 0] = v.x; row[c4 * 4 + 1] = v.y;
        row[c4 * 4 + 2] = v.z; row[c4 * 4 + 3] = v.w;
      }
      float mypiv = 1.f, myinv = 0.f;
#pragma unroll
      for (int k = 0; k < 32; ++k) {
        colbuf[l] = row[k];
        float cb[32];
#pragma unroll
        for (int q = 0; q < 8; ++q) {
          float4 v = *(const float4*)&colbuf[q * 4];
          cb[q * 4 + 0] = v.x; cb[q * 4 + 1] = v.y;
          cb[q * 4 + 2] = v.z; cb[q * 4 + 3] = v.w;
        }
        float piv = cb[k];
        float inv = rsqrtf(piv);
        inv = inv * (1.5f - 0.5f * piv * inv * inv);
        if (lane == k) { mypiv = piv; myinv = inv; }
        float tmul = row[k] * (inv * inv);
#pragma unroll
        for (int c = k + 1; c < 32; ++c)
          row[c] = fmaf(-tmul, cb[c], row[c]);
        row[k] *= inv;
      }
      if (lane < 32) {
#pragma unroll
        for (int c = 0; c < 32; ++c) PlT[c][lane] = row[c];
        invd[lane] = myinv;
      }
      lda += log((double)mypiv);
    }
    __syncthreads();
    if (tid < N2) {
      const int R = pbase + 32 + tid;
      float s[32];
#pragma unroll
      for (int c4 = 0; c4 < 8; ++c4) {
        float4 v = *(const float4*)&As[R][pbase + c4 * 4];
        s[c4 * 4 + 0] = v.x; s[c4 * 4 + 1] = v.y;
        s[c4 * 4 + 2] = v.z; s[c4 * 4 + 3] = v.w;
      }
#pragma unroll
      for (int i = 0; i < 32; ++i) {
        float xi = s[i] * invd[i];
        s[i] = xi;
#pragma unroll
        for (int jj = i + 1; jj < 32; ++jj)
          s[jj] = fmaf(-xi, PlT[i][jj], s[jj]);
      }
      unsigned hp[16], lp[16];
#pragma unroll
      for (int q = 0; q < 16; ++q) {
        short ha, la, hb, lb;
        bsplit(s[2 * q], ha, la);
        bsplit(s[2 * q + 1], hb, lb);
        hp[q] = (unsigned)(unsigned short)ha | ((unsigned)(unsigned short)hb << 16);
        lp[q] = (unsigned)(unsigned short)la | ((unsigned)(unsigned short)lb << 16);
      }
#pragma unroll
      for (int q = 0; q < 4; ++q) {
        *(int4*)&Thi[tid * 40 + q * 8] =
            make_int4(hp[4 * q], hp[4 * q + 1], hp[4 * q + 2], hp[4 * q + 3]);
        *(int4*)&Tlo[tid * 40 + q * 8] =
            make_int4(lp[4 * q], lp[4 * q + 1], lp[4 * q + 2], lp[4 * q + 3]);
      }
    }
    __syncthreads();
    const int nstr = N2 >> 5;
    if (wv < nstr) {
      const int l31 = lane & 31;
      const int h = lane >> 5;
      const int arow = wv * 32 + l31;
#pragma unroll 1
      for (int ct = 0; ct < nstr; ++ct) {
        const int brow = ct * 32 + l31;
        f32x16 acc;
#pragma unroll
        for (int i = 0; i < 16; ++i) acc[i] = 0.f;
#pragma unroll
        for (int ks = 0; ks < 2; ++ks) {
          const int off = ks * 16 + h * 8;
          bf16x8 ahi = *(const bf16x8*)&Thi[arow * 40 + off];
          bf16x8 alo = *(const bf16x8*)&Tlo[arow * 40 + off];
          bf16x8 bhi = *(const bf16x8*)&Thi[brow * 40 + off];
          bf16x8 blo = *(const bf16x8*)&Tlo[brow * 40 + off];
          acc = __builtin_amdgcn_mfma_f32_32x32x16_bf16(ahi, bhi, acc, 0, 0, 0);
          acc = __builtin_amdgcn_mfma_f32_32x32x16_bf16(ahi, blo, acc, 0, 0, 0);
          acc = __builtin_amdgcn_mfma_f32_32x32x16_bf16(alo, bhi, acc, 0, 0, 0);
        }
#pragma unroll
        for (int i = 0; i < 16; ++i) {
          int rr = pbase + 32 + wv * 32 + (i & 3) + 8 * (i >> 2) + 4 * h;
          int cc = pbase + 32 + ct * 32 + l31;
          As[rr][cc] -= acc[i];
        }
      }
    }
    __syncthreads();
  }

  if (wv == 0) red[lane] = lda;
  __syncthreads();
  if (tid == 0) {
    double lsum = 0.0;
    for (int i = 0; i < 64; ++i) lsum += red[i];
    double res;
    if (j < NCLS) {
      int mj = hist[j];
      res = 0.0;
      if (mj > 0) {
        double cj = (double)D / ((double)mj * 0.01);
        res = ((double)D * log(cj) + lsum) * (double)mj / (2.0 * (double)Mtot);
      }
    } else {
      double c = (double)D / ((double)Mtot * 0.01);
      res = ((double)D * log(c) + lsum) * 0.5;
    }
    results[j] = res;
    __threadfence();  // publish before signaling
    int done = atomicAdd(sync_ctr, 1);
    if (done == NCLS) {  // last of NCLS+1 blocks
      __threadfence();
      volatile double* vr = (volatile double*)results;
      double ssum = 0.0;
      for (int q = 0; q < NCLS; ++q) ssum += vr[q];
      out[0] = (float)(ssum - vr[NCLS]);
    }
  }
}

extern "C" void kernel_launch(void* const* d_in, const int* in_sizes, int n_in,
                              void* d_out, int out_size, void* d_ws, size_t ws_size,
                              hipStream_t stream) {
  const float* Z = (const float*)d_in[0];
  const int* label = (const int*)d_in[1];
  const int Mtot = in_sizes[1];
  float* out = (float*)d_out;
  const int NB = (Mtot + CHUNK - 1) / CHUNK;

  char* ws = (char*)d_ws;
  int* hist = (int*)(ws + 0);
  int* cstart = (int*)(ws + 256);
  int* sync_ctr = (int*)(ws + 448);
  double* results = (double*)(ws + 512);
  int* idxbuf = (int*)(ws + 1024);
  float* partials = (float*)(ws + 1024 + (size_t)Mtot * sizeof(int));
  float* covs = partials + (size_t)NCLS * TSLOT * D * D;
  int* blkhist_t = (int*)partials;  // aliased, dead before cov_k
  int* base_t = blkhist_t + (size_t)NCLS * NB;

  zero_k<<<1, 64, 0, stream>>>(hist, sync_ctr);
  hist_blk_k<<<NB, 64, 0, stream>>>(label, Mtot, NB, blkhist_t, hist);
  base_k<<<NCLS, 64, 0, stream>>>(hist, blkhist_t, NB, cstart, base_t);
  scatter2_k<<<NB, 64, 0, stream>>>(label, Mtot, NB, base_t, idxbuf);
  cov_k<<<NCLS * TSLOT, 1024, 0, stream>>>(Z, idxbuf, hist, cstart, partials);
  reduce_k<<<(D * D) / 256, 256, 0, stream>>>(partials, covs);
  chol_k<<<NCLS + 1, 256, 0, stream>>>(covs, hist, Mtot, results, sync_ctr, out);
}

// Round 15
// 124.136 us; speedup vs baseline: 1.4765x; 1.0143x over previous
//
#include <hip/hip_runtime.h>
#include <math.h>

#define D 128
#define NCLS 32
#define TSLOT 16
#define CHUNK 256  // labels per sort block

typedef float f32x16 __attribute__((ext_vector_type(16)));
typedef short bf16x8 __attribute__((ext_vector_type(8)));

// ---------------- zero counters ----------------
__global__ void zero_k(int* hist, int* sync_ctr) {
  int t = threadIdx.x;
  if (t < NCLS) hist[t] = 0;
  if (t == NCLS) *sync_ctr = 0;
}

// ---------------- per-block label histogram (+ global hist) ----------------
__global__ __launch_bounds__(64) void hist_blk_k(const int* __restrict__ label, int M,
                                                 int NB, int* __restrict__ blkhist_t,
                                                 int* __restrict__ hist) {
  __shared__ int h[NCLS];
  const int lane = threadIdx.x;
  const int b = blockIdx.x;
  if (lane < NCLS) h[lane] = 0;
  __syncthreads();
  const int s0 = b * CHUNK;
#pragma unroll
  for (int it = 0; it < CHUNK / 64; ++it) {
    int i = s0 + it * 64 + lane;
    if (i < M) atomicAdd(&h[label[i]], 1);
  }
  __syncthreads();
  if (lane < NCLS) {
    blkhist_t[lane * NB + b] = h[lane];
    atomicAdd(&hist[lane], h[lane]);
  }
}

// ---------------- per-class block scan (prefix fused via shfl over hist) -----
__global__ __launch_bounds__(64) void base_k(const int* __restrict__ hist,
                                             const int* __restrict__ blkhist_t, int NB,
                                             int* __restrict__ cstart,
                                             int* __restrict__ base_t) {
  const int j = blockIdx.x;
  const int lane = threadIdx.x;
  int h = (lane < NCLS) ? hist[lane] : 0;
  int incl = h;
#pragma unroll
  for (int off = 1; off < 32; off <<= 1) {
    int o = __shfl_up(incl, off);
    if ((lane & 31) >= off) incl += o;
  }
  int excl = incl - h;
  const int mystart = __shfl(excl, j);
  if (j == 0 && lane < NCLS) {
    cstart[lane] = excl;
    if (lane == NCLS - 1) cstart[NCLS] = incl;
  }
  const int K = (NB + 63) / 64;
  int vals[32];
  int run = 0;
  for (int k = 0; k < K; ++k) {
    int b = lane * K + k;
    int v = (b < NB) ? blkhist_t[j * NB + b] : 0;
    vals[k] = v;
    run += v;
  }
  int incl2 = run;
  for (int off = 1; off < 64; off <<= 1) {
    int o = __shfl_up(incl2, off);
    if (lane >= off) incl2 += o;
  }
  int pos = mystart + (incl2 - run);
  for (int k = 0; k < K; ++k) {
    int b = lane * K + k;
    if (b < NB) base_t[j * NB + b] = pos;
    pos += vals[k];
  }
}

// ---------------- stable, atomic-free scatter (1 wave / block) ----------------
__global__ __launch_bounds__(64) void scatter2_k(const int* __restrict__ label, int M,
                                                 int NB, const int* __restrict__ base_t,
                                                 int* __restrict__ idxbuf) {
  __shared__ int cur[NCLS];
  const int b = blockIdx.x;
  const int lane = threadIdx.x;
  if (lane < NCLS) cur[lane] = base_t[lane * NB + b];
  __syncthreads();
  const int s0 = b * CHUNK;
#pragma unroll
  for (int it = 0; it < CHUNK / 64; ++it) {
    int i = s0 + it * 64 + lane;
    int j = (i < M) ? label[i] : -1;
    unsigned long long mask = 0;
#pragma unroll
    for (int q = 0; q < NCLS; ++q) {
      unsigned long long mm = __ballot(j == q);
      if (j == q) mask = mm;
    }
    if (j >= 0) {
      int myoff = __popcll(mask & ((1ull << lane) - 1ull));
      int basec = cur[j];
      idxbuf[basec + myoff] = i;
      if (myoff == 0) cur[j] = basec + __popcll(mask);
    }
    __syncthreads();
  }
}

// ---------------- fp32 -> (hi, lo) bf16 split, RNE ----------------
__device__ inline void bsplit(float x, short& hi, short& lo) {
  unsigned u = __float_as_uint(x);
  unsigned rh = u + 0x7fffu + ((u >> 16) & 1u);
  unsigned short h = (unsigned short)(rh >> 16);
  float hf = __uint_as_float((unsigned)h << 16);
  float l = x - hf;  // exact
  unsigned ul = __float_as_uint(l);
  unsigned rl = ul + 0x7fffu + ((ul >> 16) & 1u);
  hi = (short)h;
  lo = (short)(rl >> 16);
}

// ---------------- per-class Gram via bf16-split MFMA (R11 structure) ----------
__global__ __launch_bounds__(1024, 8) void cov_k(const float* __restrict__ Z,
                                                 const int* __restrict__ idxbuf,
                                                 const int* __restrict__ hist,
                                                 const int* __restrict__ cstart,
                                                 float* __restrict__ partials) {
  __shared__ __attribute__((aligned(16))) char arena[33792];
  char* const ThiB = arena;
  char* const TloB = arena + 16896;

  const int b = blockIdx.x;
  const int cls = b / TSLOT, slot = b % TSLOT;
  const int t = threadIdx.x;
  const int lane = t & 63;
  const int w = t >> 6;
  const int r = w >> 2;  // A row-strip 0..3
  const int cq = w & 3;  // B col-strip 0..3

  const int col4 = t & 31;  // stages cols 4*col4 .. +3
  const int rg = t >> 5;    // stages rows rg*2, rg*2+1 (k dim)
  const int wbase = (((rg >> 3) * 4 + (col4 >> 3)) * 2 + ((rg >> 2) & 1)) * 528 +
                    (col4 & 7) * 16 + (rg & 3) * 4;

  const int mj = hist[cls];
  const int seg0 = cstart[cls];
  const int segend = seg0 + mj;
  const int nch = (mj + 63) / 64;

  f32x16 acc;
#pragma unroll
  for (int i = 0; i < 16; ++i) acc[i] = 0.f;

  const int n = lane & 31;
  const int poff = ((n >> 2) + 8 * (n & 3)) * 16 + (lane >> 5) * 528;

  float4 pv[2];
  int idxn0 = 0, idxn1 = 0;
  {
    const int ch = slot;
    const int r0 = seg0 + ch * 64;
    int i0 = 0, i1 = 0;
    if (ch < nch) {
      int g0 = r0 + rg * 2, g1 = r0 + rg * 2 + 1;
      if (g0 < segend) i0 = idxbuf[g0];
      if (g1 < segend) i1 = idxbuf[g1];
      pv[0] = (g0 < segend) ? *(const float4*)(Z + (size_t)i0 * D + col4 * 4)
                            : make_float4(0.f, 0.f, 0.f, 0.f);
      pv[1] = (g1 < segend) ? *(const float4*)(Z + (size_t)i1 * D + col4 * 4)
                            : make_float4(0.f, 0.f, 0.f, 0.f);
    } else {
      pv[0] = make_float4(0.f, 0.f, 0.f, 0.f);
      pv[1] = make_float4(0.f, 0.f, 0.f, 0.f);
    }
    const int chn = ch + TSLOT;
    const int r1 = seg0 + chn * 64;
    if (chn < nch) {
      int g0 = r1 + rg * 2, g1 = r1 + rg * 2 + 1;
      if (g0 < segend) idxn0 = idxbuf[g0];
      if (g1 < segend) idxn1 = idxbuf[g1];
    }
  }

#pragma unroll 1
  for (int ch = slot; ch < nch; ch += TSLOT) {
    __syncthreads();  // arena free (prior MFMA done by all waves)
    {
      float xs[2][4];
      xs[0][0] = pv[0].x; xs[0][1] = pv[0].y; xs[0][2] = pv[0].z; xs[0][3] = pv[0].w;
      xs[1][0] = pv[1].x; xs[1][1] = pv[1].y; xs[1][2] = pv[1].z; xs[1][3] = pv[1].w;
#pragma unroll
      for (int j = 0; j < 4; ++j) {
        short h0, l0, h1, l1;
        bsplit(xs[0][j], h0, l0);
        bsplit(xs[1][j], h1, l1);
        *(short2*)(ThiB + wbase + j * 128) = make_short2(h0, h1);
        *(short2*)(TloB + wbase + j * 128) = make_short2(l0, l1);
      }
    }
    __syncthreads();  // arena staged by all waves
    {
      const int chn = ch + TSLOT;
      const int r1 = seg0 + chn * 64;
      int g0 = r1 + rg * 2, g1 = r1 + rg * 2 + 1;
      bool v0 = (chn < nch) && (g0 < segend);
      bool v1 = (chn < nch) && (g1 < segend);
      pv[0] = v0 ? *(const float4*)(Z + (size_t)idxn0 * D + col4 * 4)
                 : make_float4(0.f, 0.f, 0.f, 0.f);
      pv[1] = v1 ? *(const float4*)(Z + (size_t)idxn1 * D + col4 * 4)
                 : make_float4(0.f, 0.f, 0.f, 0.f);
      const int chn2 = ch + 2 * TSLOT;
      const int r2 = seg0 + chn2 * 64;
      if (chn2 < nch) {
        int h0 = r2 + rg * 2, h1 = r2 + rg * 2 + 1;
        if (h0 < segend) idxn0 = idxbuf[h0];
        if (h1 < segend) idxn1 = idxbuf[h1];
      }
    }
#pragma unroll
    for (int kk = 0; kk < 4; ++kk) {
      const int ab = (kk * 4 + r) * 1056 + poff;
      const int bb = (kk * 4 + cq) * 1056 + poff;
      bf16x8 ahi = *(const bf16x8*)(ThiB + ab);
      bf16x8 alo = *(const bf16x8*)(TloB + ab);
      bf16x8 bhi = *(const bf16x8*)(ThiB + bb);
      bf16x8 blo = *(const bf16x8*)(TloB + bb);
      acc = __builtin_amdgcn_mfma_f32_32x32x16_bf16(ahi, bhi, acc, 0, 0, 0);
      acc = __builtin_amdgcn_mfma_f32_32x32x16_bf16(ahi, blo, acc, 0, 0, 0);
      acc = __builtin_amdgcn_mfma_f32_32x32x16_bf16(alo, bhi, acc, 0, 0, 0);
    }
  }

  size_t base = (size_t)b * (D * D);
#pragma unroll
  for (int i = 0; i < 16; ++i) {
    int prow = r * 32 + (i & 3) + 8 * (i >> 2) + 4 * (lane >> 5);
    int qcol = cq * 32 + (lane & 31);
    partials[base + (size_t)prow * D + qcol] = acc[i];
  }
}

// ---------------- reduce partials -> 32 class covs + total cov ----------------
__global__ void reduce_k(const float* __restrict__ partials, float* __restrict__ covs) {
  int e = blockIdx.x * blockDim.x + threadIdx.x;
  double tot = 0.0;
  for (int j = 0; j < NCLS; ++j) {
    double s = 0.0;
    for (int t = 0; t < TSLOT; ++t)
      s += (double)partials[(size_t)(j * TSLOT + t) * (D * D) + e];
    covs[(size_t)j * (D * D) + e] = (float)s;
    tot += s;
  }
  covs[(size_t)NCLS * (D * D) + e] = (float)tot;
}

// ---------------- blocked Cholesky logdet + fused final combine --------------
__global__ __launch_bounds__(256, 1) void chol_k(const float* __restrict__ covs,
                                                 const int* __restrict__ hist,
                                                 int Mtot, double* __restrict__ results,
                                                 int* __restrict__ sync_ctr,
                                                 float* __restrict__ out) {
  __shared__ float As[128][132];
  __shared__ float PlT[32][36];  // PlT[i][jj] = L11[jj][i]
  __shared__ float invd[32];
  __shared__ float colbuf[32];
  __shared__ double red[64];
  __shared__ int lastflag;
  __shared__ __attribute__((aligned(16))) short Thi[96 * 40];  // 80B pitch
  __shared__ __attribute__((aligned(16))) short Tlo[96 * 40];
  const int j = blockIdx.x;
  const float* A = covs + (size_t)j * (D * D);
  const int tid = threadIdx.x;
  const int lane = tid & 63;
  const int wv = tid >> 6;

#pragma unroll
  for (int it = 0; it < 16; ++it) {
    int e = it * 1024 + tid * 4;
    int r = e >> 7, c = e & 127;
    *(float4*)&As[r][c] = *(const float4*)&A[e];
  }
  __syncthreads();

  double lda = 0.0;
#pragma unroll 1
  for (int p = 0; p < 4; ++p) {
    const int pbase = p * 32;
    const int N2 = 96 - pbase;
    if (wv == 0) {
      const int l = lane & 31;
      float row[32];
#pragma unroll
      for (int c4 = 0; c4 < 8; ++c4) {
        float4 v = *(const float4*)&As[pbase + l][pbase + c4 * 4];
        row[c4 * 4 + 0] = v.x; row[c4 * 4 + 1] = v.y;
        row[c4 * 4 + 2] = v.z; row[c4 * 4 + 3] = v.w;
      }
      float mypiv = 1.f, myinv = 0.f;
#pragma unroll
      for (int k = 0; k < 32; ++k) {
        colbuf[l] = row[k];
        float cb[32];
#pragma unroll
        for (int q = 0; q < 8; ++q) {
          float4 v = *(const float4*)&colbuf[q * 4];
          cb[q * 4 + 0] = v.x; cb[q * 4 + 1] = v.y;
          cb[q * 4 + 2] = v.z; cb[q * 4 + 3] = v.w;
        }
        float piv = cb[k];
        float inv = rsqrtf(piv);
        inv = inv * (1.5f - 0.5f * piv * inv * inv);
        if (lane == k) { mypiv = piv; myinv = inv; }
        float tmul = row[k] * (inv * inv);
#pragma unroll
        for (int c = k + 1; c < 32; ++c)
          row[c] = fmaf(-tmul, cb[c], row[c]);
        row[k] *= inv;
      }
      if (lane < 32) {
#pragma unroll
        for (int c = 0; c < 32; ++c) PlT[c][lane] = row[c];
        invd[lane] = myinv;
      }
      lda += log((double)mypiv);
    }
    __syncthreads();
    if (tid < N2) {
      const int R = pbase + 32 + tid;
      float s[32];
#pragma unroll
      for (int c4 = 0; c4 < 8; ++c4) {
        float4 v = *(const float4*)&As[R][pbase + c4 * 4];
        s[c4 * 4 + 0] = v.x; s[c4 * 4 + 1] = v.y;
        s[c4 * 4 + 2] = v.z; s[c4 * 4 + 3] = v.w;
      }
#pragma unroll
      for (int i = 0; i < 32; ++i) {
        float xi = s[i] * invd[i];
        s[i] = xi;
#pragma unroll
        for (int jj = i + 1; jj < 32; ++jj)
          s[jj] = fmaf(-xi, PlT[i][jj], s[jj]);
      }
      unsigned hp[16], lp[16];
#pragma unroll
      for (int q = 0; q < 16; ++q) {
        short ha, la, hb, lb;
        bsplit(s[2 * q], ha, la);
        bsplit(s[2 * q + 1], hb, lb);
        hp[q] = (unsigned)(unsigned short)ha | ((unsigned)(unsigned short)hb << 16);
        lp[q] = (unsigned)(unsigned short)la | ((unsigned)(unsigned short)lb << 16);
      }
#pragma unroll
      for (int q = 0; q < 4; ++q) {
        *(int4*)&Thi[tid * 40 + q * 8] =
            make_int4(hp[4 * q], hp[4 * q + 1], hp[4 * q + 2], hp[4 * q + 3]);
        *(int4*)&Tlo[tid * 40 + q * 8] =
            make_int4(lp[4 * q], lp[4 * q + 1], lp[4 * q + 2], lp[4 * q + 3]);
      }
    }
    __syncthreads();
    const int nstr = N2 >> 5;
    if (wv < nstr) {
      const int l31 = lane & 31;
      const int h = lane >> 5;
      const int arow = wv * 32 + l31;
#pragma unroll 1
      for (int ct = 0; ct < nstr; ++ct) {
        const int brow = ct * 32 + l31;
        f32x16 acc;
#pragma unroll
        for (int i = 0; i < 16; ++i) acc[i] = 0.f;
#pragma unroll
        for (int ks = 0; ks < 2; ++ks) {
          const int off = ks * 16 + h * 8;
          bf16x8 ahi = *(const bf16x8*)&Thi[arow * 40 + off];
          bf16x8 alo = *(const bf16x8*)&Tlo[arow * 40 + off];
          bf16x8 bhi = *(const bf16x8*)&Thi[brow * 40 + off];
          bf16x8 blo = *(const bf16x8*)&Tlo[brow * 40 + off];
          acc = __builtin_amdgcn_mfma_f32_32x32x16_bf16(ahi, bhi, acc, 0, 0, 0);
          acc = __builtin_amdgcn_mfma_f32_32x32x16_bf16(ahi, blo, acc, 0, 0, 0);
          acc = __builtin_amdgcn_mfma_f32_32x32x16_bf16(alo, bhi, acc, 0, 0, 0);
        }
#pragma unroll
        for (int i = 0; i < 16; ++i) {
          int rr = pbase + 32 + wv * 32 + (i & 3) + 8 * (i >> 2) + 4 * h;
          int cc = pbase + 32 + ct * 32 + l31;
          As[rr][cc] -= acc[i];
        }
      }
    }
    __syncthreads();
  }

  if (wv == 0) red[lane] = lda;
  __syncthreads();
  if (tid == 0) {
    double lsum = 0.0;
    for (int i = 0; i < 64; ++i) lsum += red[i];
    double res;
    if (j < NCLS) {
      int mj = hist[j];
      res = 0.0;
      if (mj > 0) {
        double cj = (double)D / ((double)mj * 0.01);
        res = ((double)D * log(cj) + lsum) * (double)mj / (2.0 * (double)Mtot);
      }
    } else {
      double c = (double)D / ((double)Mtot * 0.01);
      res = ((double)D * log(c) + lsum) * 0.5;
    }
    results[j] = res;
    __threadfence();  // publish before signaling
    int done = atomicAdd(sync_ctr, 1);
    lastflag = (done == NCLS);  // last of NCLS+1 blocks
  }
  __syncthreads();
  if (lastflag) {
    __threadfence();  // acquire: invalidate caches before reading peers' results
    if (wv == 0) {
      // parallel volatile loads (one per lane) + shfl reduce; sign folded in
      double v = 0.0;
      if (lane <= NCLS) v = ((volatile double*)results)[lane];
      double contrib = (lane < NCLS) ? v : ((lane == NCLS) ? -v : 0.0);
#pragma unroll
      for (int off = 32; off > 0; off >>= 1) contrib += __shfl_down(contrib, off);
      if (lane == 0) out[0] = (float)contrib;
    }
  }
}

extern "C" void kernel_launch(void* const* d_in, const int* in_sizes, int n_in,
                              void* d_out, int out_size, void* d_ws, size_t ws_size,
                              hipStream_t stream) {
  const float* Z = (const float*)d_in[0];
  const int* label = (const int*)d_in[1];
  const int Mtot = in_sizes[1];
  float* out = (float*)d_out;
  const int NB = (Mtot + CHUNK - 1) / CHUNK;

  char* ws = (char*)d_ws;
  int* hist = (int*)(ws + 0);
  int* cstart = (int*)(ws + 256);
  int* sync_ctr = (int*)(ws + 448);
  double* results = (double*)(ws + 512);
  int* idxbuf = (int*)(ws + 1024);
  float* partials = (float*)(ws + 1024 + (size_t)Mtot * sizeof(int));
  float* covs = partials + (size_t)NCLS * TSLOT * D * D;
  int* blkhist_t = (int*)partials;  // aliased, dead before cov_k
  int* base_t = blkhist_t + (size_t)NCLS * NB;

  zero_k<<<1, 64, 0, stream>>>(hist, sync_ctr);
  hist_blk_k<<<NB, 64, 0, stream>>>(label, Mtot, NB, blkhist_t, hist);
  base_k<<<NCLS, 64, 0, stream>>>(hist, blkhist_t, NB, cstart, base_t);
  scatter2_k<<<NB, 64, 0, stream>>>(label, Mtot, NB, base_t, idxbuf);
  cov_k<<<NCLS * TSLOT, 1024, 0, stream>>>(Z, idxbuf, hist, cstart, partials);
  reduce_k<<<(D * D) / 256, 256, 0, stream>>>(partials, covs);
  chol_k<<<NCLS + 1, 256, 0, stream>>>(covs, hist, Mtot, results, sync_ctr, out);
}

// Round 16
// 118.295 us; speedup vs baseline: 1.5495x; 1.0494x over previous
//
#include <hip/hip_runtime.h>
#include <math.h>

#define D 128
#define NCLS 32
#define TSLOT 16
#define CHUNK 256  // labels per sort block

typedef float f32x16 __attribute__((ext_vector_type(16)));
typedef short bf16x8 __attribute__((ext_vector_type(8)));

// ---------------- zero counters ----------------
__global__ void zero_k(int* hist) {
  int t = threadIdx.x;
  if (t < NCLS) hist[t] = 0;
}

// ---------------- per-block label histogram (+ global hist) ----------------
__global__ __launch_bounds__(64) void hist_blk_k(const int* __restrict__ label, int M,
                                                 int NB, int* __restrict__ blkhist_t,
                                                 int* __restrict__ hist) {
  __shared__ int h[NCLS];
  const int lane = threadIdx.x;
  const int b = blockIdx.x;
  if (lane < NCLS) h[lane] = 0;
  __syncthreads();
  const int s0 = b * CHUNK;
#pragma unroll
  for (int it = 0; it < CHUNK / 64; ++it) {
    int i = s0 + it * 64 + lane;
    if (i < M) atomicAdd(&h[label[i]], 1);
  }
  __syncthreads();
  if (lane < NCLS) {
    blkhist_t[lane * NB + b] = h[lane];
    atomicAdd(&hist[lane], h[lane]);
  }
}

// ---------------- exclusive prefix over classes ----------------
__global__ void prefix_k(const int* __restrict__ hist, int* __restrict__ cstart) {
  if (threadIdx.x == 0) {
    int run = 0;
    for (int j = 0; j < NCLS; ++j) { cstart[j] = run; run += hist[j]; }
    cstart[NCLS] = run;
  }
}

// ---------------- per-class scan over blocks: base_t[j][b] ----------------
__global__ __launch_bounds__(64) void base_k(const int* __restrict__ blkhist_t,
                                             const int* __restrict__ cstart, int NB,
                                             int* __restrict__ base_t) {
  const int j = blockIdx.x;
  const int lane = threadIdx.x;
  const int K = (NB + 63) / 64;
  int vals[32];
  int run = 0;
  for (int k = 0; k < K; ++k) {
    int b = lane * K + k;
    int v = (b < NB) ? blkhist_t[j * NB + b] : 0;
    vals[k] = v;
    run += v;
  }
  int incl = run;
  for (int off = 1; off < 64; off <<= 1) {
    int o = __shfl_up(incl, off);
    if (lane >= off) incl += o;
  }
  int pos = cstart[j] + (incl - run);
  for (int k = 0; k < K; ++k) {
    int b = lane * K + k;
    if (b < NB) base_t[j * NB + b] = pos;
    pos += vals[k];
  }
}

// ---------------- stable, atomic-free scatter (1 wave / block) ----------------
__global__ __launch_bounds__(64) void scatter2_k(const int* __restrict__ label, int M,
                                                 int NB, const int* __restrict__ base_t,
                                                 int* __restrict__ idxbuf) {
  __shared__ int cur[NCLS];
  const int b = blockIdx.x;
  const int lane = threadIdx.x;
  if (lane < NCLS) cur[lane] = base_t[lane * NB + b];
  __syncthreads();
  const int s0 = b * CHUNK;
#pragma unroll
  for (int it = 0; it < CHUNK / 64; ++it) {
    int i = s0 + it * 64 + lane;
    int j = (i < M) ? label[i] : -1;
    unsigned long long mask = 0;
#pragma unroll
    for (int q = 0; q < NCLS; ++q) {
      unsigned long long mm = __ballot(j == q);
      if (j == q) mask = mm;
    }
    if (j >= 0) {
      int myoff = __popcll(mask & ((1ull << lane) - 1ull));
      int basec = cur[j];
      idxbuf[basec + myoff] = i;
      if (myoff == 0) cur[j] = basec + __popcll(mask);
    }
    __syncthreads();
  }
}

// ---------------- fp32 -> (hi, lo) bf16 split, RNE ----------------
__device__ inline void bsplit(float x, short& hi, short& lo) {
  unsigned u = __float_as_uint(x);
  unsigned rh = u + 0x7fffu + ((u >> 16) & 1u);
  unsigned short h = (unsigned short)(rh >> 16);
  float hf = __uint_as_float((unsigned)h << 16);
  float l = x - hf;  // exact
  unsigned ul = __float_as_uint(l);
  unsigned rl = ul + 0x7fffu + ((ul >> 16) & 1u);
  hi = (short)h;
  lo = (short)(rl >> 16);
}

// ---------------- per-class Gram via bf16-split MFMA ----------------
// 1024 threads (16 waves) per block -> 2 blocks/CU = 32 waves/CU (full wave
// occupancy). Each wave owns ONE 32x32 output tile (r = w>>2, cq = w&3) and
// accumulates the symmetric-complete hi.hi^T + hi.lo^T + lo.hi^T directly.
// Fragment-ordered LDS arena (33.8 KB, region pitch 528 B, slot bijection
// p=(n>>2)+8(n&3)). Pipeline per 64-row chunk: barrier(arena free) -> stage
// -> barrier(staged) -> issue Z(c+1) [idx already resident] + idx(c+2) -> MFMA.
__global__ __launch_bounds__(1024, 8) void cov_k(const float* __restrict__ Z,
                                                 const int* __restrict__ idxbuf,
                                                 const int* __restrict__ hist,
                                                 const int* __restrict__ cstart,
                                                 float* __restrict__ partials) {
  __shared__ __attribute__((aligned(16))) char arena[33792];
  char* const ThiB = arena;
  char* const TloB = arena + 16896;

  const int b = blockIdx.x;
  const int cls = b / TSLOT, slot = b % TSLOT;
  const int t = threadIdx.x;
  const int lane = t & 63;
  const int w = t >> 6;
  const int r = w >> 2;   // A row-strip 0..3
  const int cq = w & 3;   // B col-strip 0..3

  const int col4 = t & 31;  // stages cols 4*col4 .. +3
  const int rg = t >> 5;    // stages rows rg*2, rg*2+1 (k dim)
  const int wbase = (((rg >> 3) * 4 + (col4 >> 3)) * 2 + ((rg >> 2) & 1)) * 528 +
                    (col4 & 7) * 16 + (rg & 3) * 4;

  const int mj = hist[cls];
  const int seg0 = cstart[cls];
  const int segend = seg0 + mj;
  const int nch = (mj + 63) / 64;

  f32x16 acc;
#pragma unroll
  for (int i = 0; i < 16; ++i) acc[i] = 0.f;

  const int n = lane & 31;
  const int poff = ((n >> 2) + 8 * (n & 3)) * 16 + (lane >> 5) * 528;

  float4 pv[2];
  int idxn0 = 0, idxn1 = 0;
  {
    const int ch = slot;
    const int r0 = seg0 + ch * 64;
    int i0 = 0, i1 = 0;
    if (ch < nch) {
      int g0 = r0 + rg * 2, g1 = r0 + rg * 2 + 1;
      if (g0 < segend) i0 = idxbuf[g0];
      if (g1 < segend) i1 = idxbuf[g1];
      pv[0] = (g0 < segend) ? *(const float4*)(Z + (size_t)i0 * D + col4 * 4)
                            : make_float4(0.f, 0.f, 0.f, 0.f);
      pv[1] = (g1 < segend) ? *(const float4*)(Z + (size_t)i1 * D + col4 * 4)
                            : make_float4(0.f, 0.f, 0.f, 0.f);
    } else {
      pv[0] = make_float4(0.f, 0.f, 0.f, 0.f);
      pv[1] = make_float4(0.f, 0.f, 0.f, 0.f);
    }
    const int chn = ch + TSLOT;
    const int r1 = seg0 + chn * 64;
    if (chn < nch) {
      int g0 = r1 + rg * 2, g1 = r1 + rg * 2 + 1;
      if (g0 < segend) idxn0 = idxbuf[g0];
      if (g1 < segend) idxn1 = idxbuf[g1];
    }
  }

#pragma unroll 1
  for (int ch = slot; ch < nch; ch += TSLOT) {
    __syncthreads();  // arena free (prior MFMA done by all waves)
    {
      float xs[2][4];
      xs[0][0] = pv[0].x; xs[0][1] = pv[0].y; xs[0][2] = pv[0].z; xs[0][3] = pv[0].w;
      xs[1][0] = pv[1].x; xs[1][1] = pv[1].y; xs[1][2] = pv[1].z; xs[1][3] = pv[1].w;
#pragma unroll
      for (int j = 0; j < 4; ++j) {
        short h0, l0, h1, l1;
        bsplit(xs[0][j], h0, l0);
        bsplit(xs[1][j], h1, l1);
        *(short2*)(ThiB + wbase + j * 128) = make_short2(h0, h1);
        *(short2*)(TloB + wbase + j * 128) = make_short2(l0, l1);
      }
    }
    __syncthreads();  // arena staged by all waves
    {
      const int chn = ch + TSLOT;
      const int r1 = seg0 + chn * 64;
      int g0 = r1 + rg * 2, g1 = r1 + rg * 2 + 1;
      bool v0 = (chn < nch) && (g0 < segend);
      bool v1 = (chn < nch) && (g1 < segend);
      pv[0] = v0 ? *(const float4*)(Z + (size_t)idxn0 * D + col4 * 4)
                 : make_float4(0.f, 0.f, 0.f, 0.f);
      pv[1] = v1 ? *(const float4*)(Z + (size_t)idxn1 * D + col4 * 4)
                 : make_float4(0.f, 0.f, 0.f, 0.f);
      const int chn2 = ch + 2 * TSLOT;
      const int r2 = seg0 + chn2 * 64;
      if (chn2 < nch) {
        int h0 = r2 + rg * 2, h1 = r2 + rg * 2 + 1;
        if (h0 < segend) idxn0 = idxbuf[h0];
        if (h1 < segend) idxn1 = idxbuf[h1];
      }
    }
#pragma unroll
    for (int kk = 0; kk < 4; ++kk) {
      const int ab = (kk * 4 + r) * 1056 + poff;
      const int bb = (kk * 4 + cq) * 1056 + poff;
      bf16x8 ahi = *(const bf16x8*)(ThiB + ab);
      bf16x8 alo = *(const bf16x8*)(TloB + ab);
      bf16x8 bhi = *(const bf16x8*)(ThiB + bb);
      bf16x8 blo = *(const bf16x8*)(TloB + bb);
      acc = __builtin_amdgcn_mfma_f32_32x32x16_bf16(ahi, bhi, acc, 0, 0, 0);
      acc = __builtin_amdgcn_mfma_f32_32x32x16_bf16(ahi, blo, acc, 0, 0, 0);
      acc = __builtin_amdgcn_mfma_f32_32x32x16_bf16(alo, bhi, acc, 0, 0, 0);
    }
  }

  size_t base = (size_t)b * (D * D);
#pragma unroll
  for (int i = 0; i < 16; ++i) {
    int prow = r * 32 + (i & 3) + 8 * (i >> 2) + 4 * (lane >> 5);
    int qcol = cq * 32 + (lane & 31);
    partials[base + (size_t)prow * D + qcol] = acc[i];
  }
}

// ---------------- reduce partials -> 32 class covs + total cov ----------------
__global__ void reduce_k(const float* __restrict__ partials, float* __restrict__ covs) {
  int e = blockIdx.x * blockDim.x + threadIdx.x;
  double tot = 0.0;
  for (int j = 0; j < NCLS; ++j) {
    double s = 0.0;
    for (int t = 0; t < TSLOT; ++t)
      s += (double)partials[(size_t)(j * TSLOT + t) * (D * D) + e];
    covs[(size_t)j * (D * D) + e] = (float)s;
    tot += s;
  }
  covs[(size_t)NCLS * (D * D) + e] = (float)tot;
}

// ---------------- blocked Cholesky logdet ----------------
// One block (256 thr) per matrix. Diag: wave 0, LDS-broadcast. Solve: i-outer
// substitution, solved row kept in regs. Trailing: MFMA via hi/lo bf16 split.
__global__ __launch_bounds__(256, 1) void chol_k(const float* __restrict__ covs,
                                                 const int* __restrict__ hist,
                                                 int Mtot, double* __restrict__ results) {
  __shared__ float As[128][132];
  __shared__ float PlT[32][36];  // PlT[i][jj] = L11[jj][i]
  __shared__ float invd[32];
  __shared__ float colbuf[32];
  __shared__ double red[64];
  __shared__ __attribute__((aligned(16))) short Thi[96 * 40];  // 40-short (80B) pitch
  __shared__ __attribute__((aligned(16))) short Tlo[96 * 40];
  const int j = blockIdx.x;
  const float* A = covs + (size_t)j * (D * D);
  const int tid = threadIdx.x;
  const int lane = tid & 63;
  const int wv = tid >> 6;

#pragma unroll
  for (int it = 0; it < 16; ++it) {
    int e = it * 1024 + tid * 4;
    int r = e >> 7, c = e & 127;
    *(float4*)&As[r][c] = *(const float4*)&A[e];
  }
  __syncthreads();

  double lda = 0.0;
#pragma unroll 1
  for (int p = 0; p < 4; ++p) {
    const int pbase = p * 32;
    const int N2 = 96 - pbase;
    if (wv == 0) {
      const int l = lane & 31;
      float row[32];
#pragma unroll
      for (int c4 = 0; c4 < 8; ++c4) {
        float4 v = *(const float4*)&As[pbase + l][pbase + c4 * 4];
        row[c4 * 4 + 0] = v.x; row[c4 * 4 + 1] = v.y;
        row[c4 * 4 + 2] = v.z; row[c4 * 4 + 3] = v.w;
      }
      float mypiv = 1.f, myinv = 0.f;
#pragma unroll
      for (int k = 0; k < 32; ++k) {
        colbuf[l] = row[k];
        float cb[32];
#pragma unroll
        for (int q = 0; q < 8; ++q) {
          float4 v = *(const float4*)&colbuf[q * 4];
          cb[q * 4 + 0] = v.x; cb[q * 4 + 1] = v.y;
          cb[q * 4 + 2] = v.z; cb[q * 4 + 3] = v.w;
        }
        float piv = cb[k];
        float inv = rsqrtf(piv);
        inv = inv * (1.5f - 0.5f * piv * inv * inv);
        if (lane == k) { mypiv = piv; myinv = inv; }
        float tmul = row[k] * (inv * inv);
#pragma unroll
        for (int c = k + 1; c < 32; ++c)
          row[c] = fmaf(-tmul, cb[c], row[c]);
        row[k] *= inv;
      }
      if (lane < 32) {
#pragma unroll
        for (int c = 0; c < 32; ++c) PlT[c][lane] = row[c];
        invd[lane] = myinv;
      }
      lda += log((double)mypiv);
    }
    __syncthreads();
    if (tid < N2) {
      const int R = pbase + 32 + tid;
      float s[32];
#pragma unroll
      for (int c4 = 0; c4 < 8; ++c4) {
        float4 v = *(const float4*)&As[R][pbase + c4 * 4];
        s[c4 * 4 + 0] = v.x; s[c4 * 4 + 1] = v.y;
        s[c4 * 4 + 2] = v.z; s[c4 * 4 + 3] = v.w;
      }
#pragma unroll
      for (int i = 0; i < 32; ++i) {
        float xi = s[i] * invd[i];
        s[i] = xi;
#pragma unroll
        for (int jj = i + 1; jj < 32; ++jj)
          s[jj] = fmaf(-xi, PlT[i][jj], s[jj]);
      }
      unsigned hp[16], lp[16];
#pragma unroll
      for (int q = 0; q < 16; ++q) {
        short ha, la, hb, lb;
        bsplit(s[2 * q], ha, la);
        bsplit(s[2 * q + 1], hb, lb);
        hp[q] = (unsigned)(unsigned short)ha | ((unsigned)(unsigned short)hb << 16);
        lp[q] = (unsigned)(unsigned short)la | ((unsigned)(unsigned short)lb << 16);
      }
#pragma unroll
      for (int q = 0; q < 4; ++q) {
        *(int4*)&Thi[tid * 40 + q * 8] =
            make_int4(hp[4 * q], hp[4 * q + 1], hp[4 * q + 2], hp[4 * q + 3]);
        *(int4*)&Tlo[tid * 40 + q * 8] =
            make_int4(lp[4 * q], lp[4 * q + 1], lp[4 * q + 2], lp[4 * q + 3]);
      }
    }
    __syncthreads();
    const int nstr = N2 >> 5;
    if (wv < nstr) {
      const int l31 = lane & 31;
      const int h = lane >> 5;
      const int arow = wv * 32 + l31;
#pragma unroll 1
      for (int ct = 0; ct < nstr; ++ct) {
        const int brow = ct * 32 + l31;
        f32x16 acc;
#pragma unroll
        for (int i = 0; i < 16; ++i) acc[i] = 0.f;
#pragma unroll
        for (int ks = 0; ks < 2; ++ks) {
          const int off = ks * 16 + h * 8;
          bf16x8 ahi = *(const bf16x8*)&Thi[arow * 40 + off];
          bf16x8 alo = *(const bf16x8*)&Tlo[arow * 40 + off];
          bf16x8 bhi = *(const bf16x8*)&Thi[brow * 40 + off];
          bf16x8 blo = *(const bf16x8*)&Tlo[brow * 40 + off];
          acc = __builtin_amdgcn_mfma_f32_32x32x16_bf16(ahi, bhi, acc, 0, 0, 0);
          acc = __builtin_amdgcn_mfma_f32_32x32x16_bf16(ahi, blo, acc, 0, 0, 0);
          acc = __builtin_amdgcn_mfma_f32_32x32x16_bf16(alo, bhi, acc, 0, 0, 0);
        }
#pragma unroll
        for (int i = 0; i < 16; ++i) {
          int rr = pbase + 32 + wv * 32 + (i & 3) + 8 * (i >> 2) + 4 * h;
          int cc = pbase + 32 + ct * 32 + l31;
          As[rr][cc] -= acc[i];
        }
      }
    }
    __syncthreads();
  }

  if (wv == 0) red[lane] = lda;
  __syncthreads();
  if (tid == 0) {
    double lsum = 0.0;
    for (int i = 0; i < 64; ++i) lsum += red[i];
    if (j < NCLS) {
      int mj = hist[j];
      double res = 0.0;
      if (mj > 0) {
        double cj = (double)D / ((double)mj * 0.01);
        res = ((double)D * log(cj) + lsum) * (double)mj / (2.0 * (double)Mtot);
      }
      results[j] = res;
    } else {
      double c = (double)D / ((double)Mtot * 0.01);
      results[NCLS] = ((double)D * log(c) + lsum) * 0.5;
    }
  }
}

// ---------------- combine ----------------
__global__ void final_k(const double* __restrict__ results, float* __restrict__ out) {
  if (threadIdx.x == 0 && blockIdx.x == 0) {
    double s = 0.0;
    for (int j = 0; j < NCLS; ++j) s += results[j];
    out[0] = (float)(s - results[NCLS]);
  }
}

extern "C" void kernel_launch(void* const* d_in, const int* in_sizes, int n_in,
                              void* d_out, int out_size, void* d_ws, size_t ws_size,
                              hipStream_t stream) {
  const float* Z = (const float*)d_in[0];
  const int* label = (const int*)d_in[1];
  const int Mtot = in_sizes[1];
  float* out = (float*)d_out;
  const int NB = (Mtot + CHUNK - 1) / CHUNK;

  char* ws = (char*)d_ws;
  int* hist = (int*)(ws + 0);
  int* cstart = (int*)(ws + 256);
  double* results = (double*)(ws + 512);
  int* idxbuf = (int*)(ws + 1024);
  float* partials = (float*)(ws + 1024 + (size_t)Mtot * sizeof(int));
  float* covs = partials + (size_t)NCLS * TSLOT * D * D;
  int* blkhist_t = (int*)partials;  // aliased, dead before cov_k
  int* base_t = blkhist_t + (size_t)NCLS * NB;

  zero_k<<<1, 64, 0, stream>>>(hist);
  hist_blk_k<<<NB, 64, 0, stream>>>(label, Mtot, NB, blkhist_t, hist);
  prefix_k<<<1, 64, 0, stream>>>(hist, cstart);
  base_k<<<NCLS, 64, 0, stream>>>(blkhist_t, cstart, NB, base_t);
  scatter2_k<<<NB, 64, 0, stream>>>(label, Mtot, NB, base_t, idxbuf);
  cov_k<<<NCLS * TSLOT, 1024, 0, stream>>>(Z, idxbuf, hist, cstart, partials);
  reduce_k<<<(D * D) / 256, 256, 0, stream>>>(partials, covs);
  chol_k<<<NCLS + 1, 256, 0, stream>>>(covs, hist, Mtot, results);
  final_k<<<1, 64, 0, stream>>>(results, out);
}